// Round 8
// baseline (250.293 us; speedup 1.0000x reference)
//
#include <hip/hip_runtime.h>

#define IMG   256
#define IMG2  65536
#define NB    64
#define NB2   128

// ---------------------------------------------------------------------------
// R8: crops rebuilt as two fill-shaped streaming passes.
// Evidence (R7 diagnostic): label = 20.3 us (5.8 TB/s, at roofline);
// crops = 50.6 us (2.3 TB/s). Fast kernels on this machine (fill 6.8 TB/s,
// label 5.8) are row-linear streaming; crops interleaved 128B chunks with a
// shfl-reduce chain between load and store. Split:
//   stats_kernel : 1 thread/cell, register min/max, writes (mn,inv) to d_ws
//                  (172032 float2 = 1.31 MB).
//   crops_stream : 1 wave/output row: 7 row loads (cache-hot), 6 stats
//                  loads, 6 x 1KB contiguous stores. No shfl/LDS/barriers.
//   label_kernel : unchanged (R4), single launch.
// ---------------------------------------------------------------------------

// ws layout in float2 units: A8 @0 (65536), B8 @65536, A16 @131072 (16384),
// B16 @147456, A32 @163840 (4096), B32 @167936. total 172032.
#define WS_A8   0
#define WS_B8   65536
#define WS_A16  131072
#define WS_B16  147456
#define WS_A32  163840
#define WS_B32  167936

template <int S, int G>
__device__ __forceinline__ void cell_stats(
    const float* __restrict__ img, const float* __restrict__ heat,
    float2* __restrict__ ws, int idx, int half, int wsbase) {
    const int b  = idx / (G * G);
    const int rr = idx % (G * G);
    const int ci = rr / G;
    const int cj = rr % G;
    const int r0 = half ? max(ci * S - 4, 0) : ci * S;
    const int c0 = half ? max(cj * S - 4, 0) : cj * S;
    const float* __restrict__ p = img + (size_t)b * IMG2 + r0 * IMG + c0;
    float mn = 3.4e38f, mx = -3.4e38f;
    for (int r = 0; r < S; ++r) {
#pragma unroll
        for (int c = 0; c < S; c += 4) {
            const float4 q = *(const float4*)(p + r * IMG + c);
            mn = fminf(mn, fminf(fminf(q.x, q.y), fminf(q.z, q.w)));
            mx = fmaxf(mx, fmaxf(fmaxf(q.x, q.y), fmaxf(q.z, q.w)));
        }
    }
    const float h   = heat[(size_t)(b + half * NB) * (G * G) + ci * G + cj];
    const float inv = (h > 0.5f ? 1.0f : 0.0f) / (mx - mn + 1e-5f);
    ws[wsbase + idx] = make_float2(mn, inv);
}

// 672 blocks x 256: t<131072 s8 (A then B halves), <163840 s16, <172032 s32.
__global__ __launch_bounds__(256) void stats_kernel(
    const float* __restrict__ img,
    const float* __restrict__ heat8,
    const float* __restrict__ heat16,
    const float* __restrict__ heat32,
    float2* __restrict__ ws) {
    const int t = blockIdx.x * 256 + threadIdx.x;
    if (t < 131072) {
        const int half = t >> 16;
        cell_stats<8, 32>(img, heat32, ws, t & 65535, half,
                          half ? WS_B8 : WS_A8);
    } else if (t < 163840) {
        const int tt = t - 131072;
        const int half = tt >> 14;
        cell_stats<16, 16>(img, heat16, ws, tt & 16383, half,
                           half ? WS_B16 : WS_A16);
    } else {
        const int tt = t - 163840;
        const int half = tt >> 12;
        cell_stats<32, 8>(img, heat8, ws, tt & 4095, half,
                          half ? WS_B32 : WS_A32);
    }
}

__device__ __forceinline__ float4 nrm(float4 q, float2 st) {
    float4 o;
    o.x = (q.x - st.x) * st.y; o.y = (q.y - st.x) * st.y;
    o.z = (q.z - st.x) * st.y; o.w = (q.w - st.x) * st.y;
    return o;
}

// 4096 blocks x 256: wave = one output row (b, u). 6 x 1KB contiguous
// stores per wave (A+B for 3 scales). B col shift = select(q0, qm).
__global__ __launch_bounds__(256) void crops_stream_kernel(
    const float* __restrict__ img,
    const float2* __restrict__ ws,
    float* __restrict__ out) {
    const int w    = threadIdx.x >> 6;
    const int lane = threadIdx.x & 63;
    const int lid  = blockIdx.x * 4 + w;    // 0..16383
    const int b    = lid >> 8;
    const int u    = lid & 255;
    const int v0   = lane << 2;
    const int vm   = max(v0 - 4, 0);

    const float* __restrict__ ip = img + (size_t)b * IMG2;

    // B-source rows per scale: max((u/S)*S-4,0) + u%S
    const int u8  = ((u >> 3) ? (u & ~7)  - 4 : 0) + (u & 7);
    const int u16 = ((u >> 4) ? (u & ~15) - 4 : 0) + (u & 15);
    const int u32 = ((u >> 5) ? (u & ~31) - 4 : 0) + (u & 31);

    const float4 xa  = *(const float4*)(ip + u   * IMG + v0);
    const float4 q08 = *(const float4*)(ip + u8  * IMG + v0);
    const float4 qm8 = *(const float4*)(ip + u8  * IMG + vm);
    const float4 q16 = *(const float4*)(ip + u16 * IMG + v0);
    const float4 qm6 = *(const float4*)(ip + u16 * IMG + vm);
    const float4 q32 = *(const float4*)(ip + u32 * IMG + v0);
    const float4 qm2 = *(const float4*)(ip + u32 * IMG + vm);

    const float2 a8  = ws[WS_A8  + ((b << 5) + (u >> 3)) * 32 + (v0 >> 3)];
    const float2 b8  = ws[WS_B8  + ((b << 5) + (u >> 3)) * 32 + (v0 >> 3)];
    const float2 a16 = ws[WS_A16 + ((b << 4) + (u >> 4)) * 16 + (v0 >> 4)];
    const float2 b16 = ws[WS_B16 + ((b << 4) + (u >> 4)) * 16 + (v0 >> 4)];
    const float2 a32 = ws[WS_A32 + ((b << 3) + (u >> 5)) *  8 + (v0 >> 5)];
    const float2 b32 = ws[WS_B32 + ((b << 3) + (u >> 5)) *  8 + (v0 >> 5)];

    const float4 s8v = (v0 < 8)  ? q08 : qm8;
    const float4 s16v = (v0 < 16) ? q16 : qm6;
    const float4 s32v = (v0 < 32) ? q32 : qm2;

    const size_t rowA = (size_t)b * IMG2 + u * IMG + v0;
    const size_t rowB = (size_t)(b + NB) * IMG2 + u * IMG + v0;
    float* __restrict__ c32 = out;                           // s=8 grid
    float* __restrict__ c16 = out + (size_t)NB2 * IMG2;      // s=16
    float* __restrict__ c8  = out + (size_t)2 * NB2 * IMG2;  // s=32

    *(float4*)(c32 + rowA) = nrm(xa,  a8);
    *(float4*)(c32 + rowB) = nrm(s8v, b8);
    *(float4*)(c16 + rowA) = nrm(xa,  a16);
    *(float4*)(c16 + rowB) = nrm(s16v, b16);
    *(float4*)(c8  + rowA) = nrm(xa,  a32);
    *(float4*)(c8  + rowB) = nrm(s32v, b32);
}

// ---------------------------------------------------------------------------
// label: one wave per row, 4 px per lane, float4 loads/stores. (R4, proven)
// ---------------------------------------------------------------------------
__device__ __forceinline__ void label_rows(
    const float* __restrict__ heat8,
    const float* __restrict__ heat16,
    const float* __restrict__ heat32,
    const float* __restrict__ seg8,
    const float* __restrict__ seg16,
    const float* __restrict__ seg32,
    float* __restrict__ out,
    int b, int u0) {
    const int wave = threadIdx.x >> 6;
    const int lane = threadIdx.x & 63;
    const int u    = u0 + wave;
    const int v0   = lane << 2;
    const int vs   = min(v0 + 4, 252);   // shifted-load base, clamped

    float nu[4] = {0.f, 0.f, 0.f, 0.f};
    float de[4] = {0.f, 0.f, 0.f, 0.f};

    if (u0 >= 32 && u0 <= 248) {
        const int i1 = u + 4;
#define SCALE_F(heat, seg, g, l, s)                                           \
        {                                                                     \
            const float* __restrict__ h1 = heat + b * (g * g);                \
            const float* __restrict__ h2 = heat + (NB + b) * (g * g);         \
            const float* __restrict__ r1 = seg + (size_t)b * IMG2 + u * IMG;  \
            const float* __restrict__ r2 =                                    \
                seg + (size_t)(NB + b) * IMG2 + i1 * IMG;                     \
            const float4 sd  = *(const float4*)(r1 + v0);                     \
            const float4 sg0 = *(const float4*)(r2 + v0);                     \
            const float4 sg1 = *(const float4*)(r2 + vs);                     \
            const float hd  = h1[(u >> l) * g + (v0 >> l)];                   \
            const float hg0 = h2[(i1 >> l) * g + (v0 >> l)];                  \
            const float hg1 = h2[(i1 >> l) * g + (vs >> l)];                  \
            const float md = (hd > 0.5f) ? 1.0f : 0.0f;                       \
            const float g0 = (hg0 > 0.5f) ? 1.0f : 0.0f;                      \
            const float g1 = (hg1 > 0.5f) ? 1.0f : 0.0f;                      \
            _Pragma("unroll")                                                 \
            for (int c = 0; c < 4; ++c) {                                     \
                const int v = v0 + c;                                         \
                const float m0 = (v < (s)) ? g0 : 0.0f;                       \
                const float m1 = (v >= (s) - 4 && v <= 251) ? g1 : 0.0f;      \
                float x = ((const float*)&sd)[c] * md;                        \
                x = fmaf(m0, ((const float*)&sg0)[c], x);                     \
                x = fmaf(m1, ((const float*)&sg1)[c], x);                     \
                nu[c] += x;                                                   \
                de[c] += md + m0 + m1;                                        \
            }                                                                 \
        }
        SCALE_F(heat32, seg32, 32, 3, 8)
        SCALE_F(heat16, seg16, 16, 4, 16)
        SCALE_F(heat8,  seg8,  8,  5, 32)
#undef SCALE_F
    } else {
        const int i0  = u;
        const int i1c = min(u + 4, 255);
#define SCALE_G(heat, seg, g, l, s)                                           \
        {                                                                     \
            const float* __restrict__ h1 = heat + b * (g * g);                \
            const float* __restrict__ h2 = heat + (NB + b) * (g * g);         \
            const float* __restrict__ r1 = seg + (size_t)b * IMG2 + u * IMG;  \
            const float* __restrict__ ra =                                    \
                seg + (size_t)(NB + b) * IMG2 + i0 * IMG;                     \
            const float* __restrict__ rb =                                    \
                seg + (size_t)(NB + b) * IMG2 + i1c * IMG;                    \
            const float4 sd  = *(const float4*)(r1 + v0);                     \
            const float4 a0q = *(const float4*)(ra + v0);                     \
            const float4 a1q = *(const float4*)(ra + vs);                     \
            const float4 b0q = *(const float4*)(rb + v0);                     \
            const float4 b1q = *(const float4*)(rb + vs);                     \
            const float hd  = h1[(u >> l) * g + (v0 >> l)];                   \
            const float hA0 = h2[(i0 >> l) * g + (v0 >> l)];                  \
            const float hA1 = h2[(i0 >> l) * g + (vs >> l)];                  \
            const float hB0 = h2[(i1c >> l) * g + (v0 >> l)];                 \
            const float hB1 = h2[(i1c >> l) * g + (vs >> l)];                 \
            const float miA = (u < (s)) ? 1.0f : 0.0f;                        \
            const float miB = (u >= (s) - 4 && u <= 251) ? 1.0f : 0.0f;       \
            const float md  = (hd > 0.5f) ? 1.0f : 0.0f;                      \
            const float gA0 = miA * ((hA0 > 0.5f) ? 1.0f : 0.0f);             \
            const float gA1 = miA * ((hA1 > 0.5f) ? 1.0f : 0.0f);             \
            const float gB0 = miB * ((hB0 > 0.5f) ? 1.0f : 0.0f);             \
            const float gB1 = miB * ((hB1 > 0.5f) ? 1.0f : 0.0f);             \
            _Pragma("unroll")                                                 \
            for (int c = 0; c < 4; ++c) {                                     \
                const int v = v0 + c;                                         \
                const float mj0 = (v < (s)) ? 1.0f : 0.0f;                    \
                const float mj1 = (v >= (s) - 4 && v <= 251) ? 1.0f : 0.0f;   \
                const float w00 = gA0 * mj0, w01 = gA1 * mj1;                 \
                const float w10 = gB0 * mj0, w11 = gB1 * mj1;                 \
                float x = ((const float*)&sd)[c] * md;                        \
                x = fmaf(w00, ((const float*)&a0q)[c], x);                    \
                x = fmaf(w01, ((const float*)&a1q)[c], x);                    \
                x = fmaf(w10, ((const float*)&b0q)[c], x);                    \
                x = fmaf(w11, ((const float*)&b1q)[c], x);                    \
                nu[c] += x;                                                   \
                de[c] += md + w00 + w01 + w10 + w11;                          \
            }                                                                 \
        }
        SCALE_G(heat32, seg32, 32, 3, 8)
        SCALE_G(heat16, seg16, 16, 4, 16)
        SCALE_G(heat8,  seg8,  8,  5, 32)
#undef SCALE_G
    }

    float4 o;
    o.x = nu[0] / (de[0] + 1e-10f);
    o.y = nu[1] / (de[1] + 1e-10f);
    o.z = nu[2] / (de[2] + 1e-10f);
    o.w = nu[3] / (de[3] + 1e-10f);
    *(float4*)(out + (size_t)b * IMG2 + u * IMG + v0) = o;
}

__global__ __launch_bounds__(256) void label_kernel(
    const float* __restrict__ heat8,
    const float* __restrict__ heat16,
    const float* __restrict__ heat32,
    const float* __restrict__ seg8,
    const float* __restrict__ seg16,
    const float* __restrict__ seg32,
    float* __restrict__ out) {
    float* label = out + (size_t)3 * NB2 * IMG2;    // (64,1,256,256)
    const int t  = blockIdx.x;                      // 0 .. 4095
    label_rows(heat8, heat16, heat32, seg8, seg16, seg32, label,
               t >> 6, (t & 63) << 2);
}

extern "C" void kernel_launch(void* const* d_in, const int* in_sizes, int n_in,
                              void* d_out, int out_size, void* d_ws, size_t ws_size,
                              hipStream_t stream) {
    const float* img    = (const float*)d_in[0];
    const float* heat8  = (const float*)d_in[1];
    const float* heat16 = (const float*)d_in[2];
    const float* heat32 = (const float*)d_in[3];
    const float* seg8   = (const float*)d_in[4];
    const float* seg16  = (const float*)d_in[5];
    const float* seg32  = (const float*)d_in[6];

    stats_kernel<<<dim3(672), 256, 0, stream>>>(
        img, heat8, heat16, heat32, (float2*)d_ws);
    crops_stream_kernel<<<dim3(4096), 256, 0, stream>>>(
        img, (const float2*)d_ws, (float*)d_out);
    label_kernel<<<dim3(4096), 256, 0, stream>>>(
        heat8, heat16, heat32, seg8, seg16, seg32, (float*)d_out);
}

// Round 9
// 231.905 us; speedup vs baseline: 1.0793x; 1.0793x over previous
//
#include <hip/hip_runtime.h>

#define IMG   256
#define IMG2  65536
#define NB    64
#define NB2   128

// ---------------------------------------------------------------------------
// R9: crops = 3 fill-shaped passes, all single-linear-stream per wave.
// Evidence: fill 6.8 TB/s & label 5.8 TB/s both use 1 region/wave; all slow
// crops variants used 2-6 regions/wave. R8's stats pass also had a
// latency-bound tail (serial per-thread row loops). Fix both:
//   blk_kernel   : img -> 4x4-block (mn,mx); wave = 4-row band, lane owns a
//                  4x4 block in registers. DIS=4 => every cell (A/B, all
//                  scales) is a union of 4-aligned 4x4 blocks.
//   cells_kernel : combine blocks -> (mn, inv) per cell (L2-hot, <=64 reads).
//   crops_stream : 6 grid-phases, one output region each; wave = one row:
//                  1x1KB load + stats + 1x1KB store. B col shift is a single
//                  computable address (v0<S ? v0 : v0-4).
//   label_kernel : unchanged (R4; 20.3 us, at roofline).
// ws float2 layout: 6 cell tables then blk table; total 434176 f2 = 3.5 MB.
// ---------------------------------------------------------------------------
#define WS_A8   0
#define WS_B8   65536
#define WS_A16  131072
#define WS_B16  147456
#define WS_A32  163840
#define WS_B32  167936
#define WS_BLK  172032   // [64][64][64] float2

// pass 1a: 1024 blocks x 256. wave = (b, 4-row band). 4 coalesced 1KB loads,
// per-lane 4x4 min/max in registers, 512B contiguous store.
__global__ __launch_bounds__(256) void blk_kernel(
    const float* __restrict__ img, float2* __restrict__ ws) {
    const int wid  = blockIdx.x * 4 + (threadIdx.x >> 6);  // 0..4095
    const int lane = threadIdx.x & 63;
    const int b    = wid >> 6;
    const int r4   = wid & 63;
    const float* __restrict__ p =
        img + (size_t)b * IMG2 + (r4 * 4) * IMG + lane * 4;
    const float4 q0 = *(const float4*)(p);
    const float4 q1 = *(const float4*)(p + IMG);
    const float4 q2 = *(const float4*)(p + 2 * IMG);
    const float4 q3 = *(const float4*)(p + 3 * IMG);
    const float mn01 = fminf(fminf(fminf(q0.x, q0.y), fminf(q0.z, q0.w)),
                             fminf(fminf(q1.x, q1.y), fminf(q1.z, q1.w)));
    const float mn23 = fminf(fminf(fminf(q2.x, q2.y), fminf(q2.z, q2.w)),
                             fminf(fminf(q3.x, q3.y), fminf(q3.z, q3.w)));
    const float mx01 = fmaxf(fmaxf(fmaxf(q0.x, q0.y), fmaxf(q0.z, q0.w)),
                             fmaxf(fmaxf(q1.x, q1.y), fmaxf(q1.z, q1.w)));
    const float mx23 = fmaxf(fmaxf(fmaxf(q2.x, q2.y), fmaxf(q2.z, q2.w)),
                             fmaxf(fmaxf(q3.x, q3.y), fmaxf(q3.z, q3.w)));
    ws[WS_BLK + (b << 12) + (r4 << 6) + lane] =
        make_float2(fminf(mn01, mn23), fmaxf(mx01, mx23));
}

template <int SH>
__device__ __forceinline__ float2 combine_blk(
    const float2* __restrict__ blk, int b, int p0, int q0) {
    float mn = 3.4e38f, mx = -3.4e38f;
    for (int i = 0; i < SH; ++i) {
#pragma unroll
        for (int j = 0; j < SH; ++j) {
            const float2 v = blk[(b << 12) + ((p0 + i) << 6) + (q0 + j)];
            mn = fminf(mn, v.x);
            mx = fmaxf(mx, v.y);
        }
    }
    return make_float2(mn, mx);
}

__device__ __forceinline__ float2 finish(float2 c, float h) {
    return make_float2(c.x, (h > 0.5f ? 1.0f : 0.0f) / (c.y - c.x + 1e-5f));
}

// pass 1b: 672 blocks x 256 = 172032 threads, one cell each.
__global__ __launch_bounds__(256) void cells_kernel(
    const float* __restrict__ heat8,
    const float* __restrict__ heat16,
    const float* __restrict__ heat32,
    float2* __restrict__ ws) {
    const float2* __restrict__ blk = ws + WS_BLK;
    const int t = blockIdx.x * 256 + threadIdx.x;
    if (t < 131072) {                       // s8 (g=32): A then B half
        const int idx = t & 65535;
        const int half = t >> 16;
        const int b = idx >> 10, ci = (idx >> 5) & 31, cj = idx & 31;
        const int p0 = half ? max(2 * ci - 1, 0) : 2 * ci;
        const int q0 = half ? max(2 * cj - 1, 0) : 2 * cj;
        const float2 c = combine_blk<2>(blk, b, p0, q0);
        const float h = heat32[(size_t)(b + half * NB) * 1024 + ci * 32 + cj];
        ws[(half ? WS_B8 : WS_A8) + idx] = finish(c, h);
    } else if (t < 163840) {                // s16 (g=16)
        const int tt = t - 131072;
        const int idx = tt & 16383;
        const int half = tt >> 14;
        const int b = idx >> 8, ci = (idx >> 4) & 15, cj = idx & 15;
        const int p0 = half ? max(4 * ci - 1, 0) : 4 * ci;
        const int q0 = half ? max(4 * cj - 1, 0) : 4 * cj;
        const float2 c = combine_blk<4>(blk, b, p0, q0);
        const float h = heat16[(size_t)(b + half * NB) * 256 + ci * 16 + cj];
        ws[(half ? WS_B16 : WS_A16) + idx] = finish(c, h);
    } else {                                // s32 (g=8)
        const int tt = t - 163840;
        const int idx = tt & 4095;
        const int half = tt >> 12;
        const int b = idx >> 6, ci = (idx >> 3) & 7, cj = idx & 7;
        const int p0 = half ? max(8 * ci - 1, 0) : 8 * ci;
        const int q0 = half ? max(8 * cj - 1, 0) : 8 * cj;
        const float2 c = combine_blk<8>(blk, b, p0, q0);
        const float h = heat8[(size_t)(b + half * NB) * 64 + ci * 8 + cj];
        ws[(half ? WS_B32 : WS_A32) + idx] = finish(c, h);
    }
}

// pass 2: 24576 blocks x 256. phase = bid>>12 picks ONE output region;
// wave = one output row: 1x1KB load + 1 stats load + 1x1KB store.
__global__ __launch_bounds__(256) void crops_stream_kernel(
    const float* __restrict__ img,
    const float2* __restrict__ ws,
    float* __restrict__ out) {
    const int phase = blockIdx.x >> 12;                        // 0..5
    const int lid = (blockIdx.x & 4095) * 4 + (threadIdx.x >> 6);
    const int b = lid >> 8, u = lid & 255;
    const int lane = threadIdx.x & 63, v0 = lane << 2;

    const float* __restrict__ ip = img + (size_t)b * IMG2;
    float* __restrict__ c32 = out;                             // s=8 grid
    float* __restrict__ c16 = out + (size_t)NB2 * IMG2;        // s=16
    float* __restrict__ c8  = out + (size_t)2 * NB2 * IMG2;    // s=32

    int srow, scol;
    float2 st;
    float* optr;
    switch (phase) {
    case 0:
        srow = u; scol = v0;
        st = ws[WS_A8 + (b << 10) + ((u >> 3) << 5) + (v0 >> 3)];
        optr = c32 + (size_t)b * IMG2;
        break;
    case 1:
        srow = ((u >> 3) ? (u & ~7) - 4 : 0) + (u & 7);
        scol = (v0 < 8) ? v0 : v0 - 4;
        st = ws[WS_B8 + (b << 10) + ((u >> 3) << 5) + (v0 >> 3)];
        optr = c32 + (size_t)(b + NB) * IMG2;
        break;
    case 2:
        srow = u; scol = v0;
        st = ws[WS_A16 + (b << 8) + ((u >> 4) << 4) + (v0 >> 4)];
        optr = c16 + (size_t)b * IMG2;
        break;
    case 3:
        srow = ((u >> 4) ? (u & ~15) - 4 : 0) + (u & 15);
        scol = (v0 < 16) ? v0 : v0 - 4;
        st = ws[WS_B16 + (b << 8) + ((u >> 4) << 4) + (v0 >> 4)];
        optr = c16 + (size_t)(b + NB) * IMG2;
        break;
    case 4:
        srow = u; scol = v0;
        st = ws[WS_A32 + (b << 6) + ((u >> 5) << 3) + (v0 >> 5)];
        optr = c8 + (size_t)b * IMG2;
        break;
    default:
        srow = ((u >> 5) ? (u & ~31) - 4 : 0) + (u & 31);
        scol = (v0 < 32) ? v0 : v0 - 4;
        st = ws[WS_B32 + (b << 6) + ((u >> 5) << 3) + (v0 >> 5)];
        optr = c8 + (size_t)(b + NB) * IMG2;
        break;
    }
    const float4 q = *(const float4*)(ip + srow * IMG + scol);
    float4 o;
    o.x = (q.x - st.x) * st.y; o.y = (q.y - st.x) * st.y;
    o.z = (q.z - st.x) * st.y; o.w = (q.w - st.x) * st.y;
    *(float4*)(optr + u * IMG + v0) = o;
}

// ---------------------------------------------------------------------------
// label: one wave per row, 4 px per lane, float4 loads/stores. (R4, proven)
// ---------------------------------------------------------------------------
__device__ __forceinline__ void label_rows(
    const float* __restrict__ heat8,
    const float* __restrict__ heat16,
    const float* __restrict__ heat32,
    const float* __restrict__ seg8,
    const float* __restrict__ seg16,
    const float* __restrict__ seg32,
    float* __restrict__ out,
    int b, int u0) {
    const int wave = threadIdx.x >> 6;
    const int lane = threadIdx.x & 63;
    const int u    = u0 + wave;
    const int v0   = lane << 2;
    const int vs   = min(v0 + 4, 252);

    float nu[4] = {0.f, 0.f, 0.f, 0.f};
    float de[4] = {0.f, 0.f, 0.f, 0.f};

    if (u0 >= 32 && u0 <= 248) {
        const int i1 = u + 4;
#define SCALE_F(heat, seg, g, l, s)                                           \
        {                                                                     \
            const float* __restrict__ h1 = heat + b * (g * g);                \
            const float* __restrict__ h2 = heat + (NB + b) * (g * g);         \
            const float* __restrict__ r1 = seg + (size_t)b * IMG2 + u * IMG;  \
            const float* __restrict__ r2 =                                    \
                seg + (size_t)(NB + b) * IMG2 + i1 * IMG;                     \
            const float4 sd  = *(const float4*)(r1 + v0);                     \
            const float4 sg0 = *(const float4*)(r2 + v0);                     \
            const float4 sg1 = *(const float4*)(r2 + vs);                     \
            const float hd  = h1[(u >> l) * g + (v0 >> l)];                   \
            const float hg0 = h2[(i1 >> l) * g + (v0 >> l)];                  \
            const float hg1 = h2[(i1 >> l) * g + (vs >> l)];                  \
            const float md = (hd > 0.5f) ? 1.0f : 0.0f;                       \
            const float g0 = (hg0 > 0.5f) ? 1.0f : 0.0f;                      \
            const float g1 = (hg1 > 0.5f) ? 1.0f : 0.0f;                      \
            _Pragma("unroll")                                                 \
            for (int c = 0; c < 4; ++c) {                                     \
                const int v = v0 + c;                                         \
                const float m0 = (v < (s)) ? g0 : 0.0f;                       \
                const float m1 = (v >= (s) - 4 && v <= 251) ? g1 : 0.0f;      \
                float x = ((const float*)&sd)[c] * md;                        \
                x = fmaf(m0, ((const float*)&sg0)[c], x);                     \
                x = fmaf(m1, ((const float*)&sg1)[c], x);                     \
                nu[c] += x;                                                   \
                de[c] += md + m0 + m1;                                        \
            }                                                                 \
        }
        SCALE_F(heat32, seg32, 32, 3, 8)
        SCALE_F(heat16, seg16, 16, 4, 16)
        SCALE_F(heat8,  seg8,  8,  5, 32)
#undef SCALE_F
    } else {
        const int i0  = u;
        const int i1c = min(u + 4, 255);
#define SCALE_G(heat, seg, g, l, s)                                           \
        {                                                                     \
            const float* __restrict__ h1 = heat + b * (g * g);                \
            const float* __restrict__ h2 = heat + (NB + b) * (g * g);         \
            const float* __restrict__ r1 = seg + (size_t)b * IMG2 + u * IMG;  \
            const float* __restrict__ ra =                                    \
                seg + (size_t)(NB + b) * IMG2 + i0 * IMG;                     \
            const float* __restrict__ rb =                                    \
                seg + (size_t)(NB + b) * IMG2 + i1c * IMG;                    \
            const float4 sd  = *(const float4*)(r1 + v0);                     \
            const float4 a0q = *(const float4*)(ra + v0);                     \
            const float4 a1q = *(const float4*)(ra + vs);                     \
            const float4 b0q = *(const float4*)(rb + v0);                     \
            const float4 b1q = *(const float4*)(rb + vs);                     \
            const float hd  = h1[(u >> l) * g + (v0 >> l)];                   \
            const float hA0 = h2[(i0 >> l) * g + (v0 >> l)];                  \
            const float hA1 = h2[(i0 >> l) * g + (vs >> l)];                  \
            const float hB0 = h2[(i1c >> l) * g + (v0 >> l)];                 \
            const float hB1 = h2[(i1c >> l) * g + (vs >> l)];                 \
            const float miA = (u < (s)) ? 1.0f : 0.0f;                        \
            const float miB = (u >= (s) - 4 && u <= 251) ? 1.0f : 0.0f;       \
            const float md  = (hd > 0.5f) ? 1.0f : 0.0f;                      \
            const float gA0 = miA * ((hA0 > 0.5f) ? 1.0f : 0.0f);             \
            const float gA1 = miA * ((hA1 > 0.5f) ? 1.0f : 0.0f);             \
            const float gB0 = miB * ((hB0 > 0.5f) ? 1.0f : 0.0f);             \
            const float gB1 = miB * ((hB1 > 0.5f) ? 1.0f : 0.0f);             \
            _Pragma("unroll")                                                 \
            for (int c = 0; c < 4; ++c) {                                     \
                const int v = v0 + c;                                         \
                const float mj0 = (v < (s)) ? 1.0f : 0.0f;                    \
                const float mj1 = (v >= (s) - 4 && v <= 251) ? 1.0f : 0.0f;   \
                const float w00 = gA0 * mj0, w01 = gA1 * mj1;                 \
                const float w10 = gB0 * mj0, w11 = gB1 * mj1;                 \
                float x = ((const float*)&sd)[c] * md;                        \
                x = fmaf(w00, ((const float*)&a0q)[c], x);                    \
                x = fmaf(w01, ((const float*)&a1q)[c], x);                    \
                x = fmaf(w10, ((const float*)&b0q)[c], x);                    \
                x = fmaf(w11, ((const float*)&b1q)[c], x);                    \
                nu[c] += x;                                                   \
                de[c] += md + w00 + w01 + w10 + w11;                          \
            }                                                                 \
        }
        SCALE_G(heat32, seg32, 32, 3, 8)
        SCALE_G(heat16, seg16, 16, 4, 16)
        SCALE_G(heat8,  seg8,  8,  5, 32)
#undef SCALE_G
    }

    float4 o;
    o.x = nu[0] / (de[0] + 1e-10f);
    o.y = nu[1] / (de[1] + 1e-10f);
    o.z = nu[2] / (de[2] + 1e-10f);
    o.w = nu[3] / (de[3] + 1e-10f);
    *(float4*)(out + (size_t)b * IMG2 + u * IMG + v0) = o;
}

__global__ __launch_bounds__(256) void label_kernel(
    const float* __restrict__ heat8,
    const float* __restrict__ heat16,
    const float* __restrict__ heat32,
    const float* __restrict__ seg8,
    const float* __restrict__ seg16,
    const float* __restrict__ seg32,
    float* __restrict__ out) {
    float* label = out + (size_t)3 * NB2 * IMG2;    // (64,1,256,256)
    const int t  = blockIdx.x;                      // 0 .. 4095
    label_rows(heat8, heat16, heat32, seg8, seg16, seg32, label,
               t >> 6, (t & 63) << 2);
}

extern "C" void kernel_launch(void* const* d_in, const int* in_sizes, int n_in,
                              void* d_out, int out_size, void* d_ws, size_t ws_size,
                              hipStream_t stream) {
    const float* img    = (const float*)d_in[0];
    const float* heat8  = (const float*)d_in[1];
    const float* heat16 = (const float*)d_in[2];
    const float* heat32 = (const float*)d_in[3];
    const float* seg8   = (const float*)d_in[4];
    const float* seg16  = (const float*)d_in[5];
    const float* seg32  = (const float*)d_in[6];
    float2* ws = (float2*)d_ws;

    blk_kernel<<<dim3(1024), 256, 0, stream>>>(img, ws);
    cells_kernel<<<dim3(672), 256, 0, stream>>>(heat8, heat16, heat32, ws);
    crops_stream_kernel<<<dim3(24576), 256, 0, stream>>>(
        img, (const float2*)ws, (float*)d_out);
    label_kernel<<<dim3(4096), 256, 0, stream>>>(
        heat8, heat16, heat32, seg8, seg16, seg32, (float*)d_out);
}

// Round 10
// 228.213 us; speedup vs baseline: 1.0967x; 1.0162x over previous
//
#include <hip/hip_runtime.h>

#define IMG   256
#define IMG2  65536
#define NB    64
#define NB2   128

// ---------------------------------------------------------------------------
// R10: crops stream rebuilt as a persistent phase-outer grid-stride kernel
// (fill-kernel shape: 2048 blocks, long per-thread store runs).
// R9 evidence: single-region streaming moved bytes at ~3.8 TB/s (best crops
// structure yet) but re-read img 6x (+100 MB). Fix: whole machine sweeps one
// output region at a time; phase 0 reads img from HBM once, phases 1-5 hit
// L3 (re-read within ~us, only ~17 MB of stores intervene per phase).
//   blk_kernel   : img -> 4x4-block (mn,mx). (unchanged, small)
//   cells_kernel : blocks -> per-cell (mn, inv) tables. (unchanged, small)
//   crops_stream : 2048 blocks x 256; 6 phases x 2 grid-stride steps,
//                  fully unrolled; 1KB load + 1KB store per step.
//   label_kernel : unchanged (R4; 20.3 us, at roofline).
// ---------------------------------------------------------------------------
#define WS_A8   0
#define WS_B8   65536
#define WS_A16  131072
#define WS_B16  147456
#define WS_A32  163840
#define WS_B32  167936
#define WS_BLK  172032   // [64][64][64] float2

__global__ __launch_bounds__(256) void blk_kernel(
    const float* __restrict__ img, float2* __restrict__ ws) {
    const int wid  = blockIdx.x * 4 + (threadIdx.x >> 6);  // 0..4095
    const int lane = threadIdx.x & 63;
    const int b    = wid >> 6;
    const int r4   = wid & 63;
    const float* __restrict__ p =
        img + (size_t)b * IMG2 + (r4 * 4) * IMG + lane * 4;
    const float4 q0 = *(const float4*)(p);
    const float4 q1 = *(const float4*)(p + IMG);
    const float4 q2 = *(const float4*)(p + 2 * IMG);
    const float4 q3 = *(const float4*)(p + 3 * IMG);
    const float mn01 = fminf(fminf(fminf(q0.x, q0.y), fminf(q0.z, q0.w)),
                             fminf(fminf(q1.x, q1.y), fminf(q1.z, q1.w)));
    const float mn23 = fminf(fminf(fminf(q2.x, q2.y), fminf(q2.z, q2.w)),
                             fminf(fminf(q3.x, q3.y), fminf(q3.z, q3.w)));
    const float mx01 = fmaxf(fmaxf(fmaxf(q0.x, q0.y), fmaxf(q0.z, q0.w)),
                             fmaxf(fmaxf(q1.x, q1.y), fmaxf(q1.z, q1.w)));
    const float mx23 = fmaxf(fmaxf(fmaxf(q2.x, q2.y), fmaxf(q2.z, q2.w)),
                             fmaxf(fmaxf(q3.x, q3.y), fmaxf(q3.z, q3.w)));
    ws[WS_BLK + (b << 12) + (r4 << 6) + lane] =
        make_float2(fminf(mn01, mn23), fmaxf(mx01, mx23));
}

template <int SH>
__device__ __forceinline__ float2 combine_blk(
    const float2* __restrict__ blk, int b, int p0, int q0) {
    float mn = 3.4e38f, mx = -3.4e38f;
    for (int i = 0; i < SH; ++i) {
#pragma unroll
        for (int j = 0; j < SH; ++j) {
            const float2 v = blk[(b << 12) + ((p0 + i) << 6) + (q0 + j)];
            mn = fminf(mn, v.x);
            mx = fmaxf(mx, v.y);
        }
    }
    return make_float2(mn, mx);
}

__device__ __forceinline__ float2 finish(float2 c, float h) {
    return make_float2(c.x, (h > 0.5f ? 1.0f : 0.0f) / (c.y - c.x + 1e-5f));
}

__global__ __launch_bounds__(256) void cells_kernel(
    const float* __restrict__ heat8,
    const float* __restrict__ heat16,
    const float* __restrict__ heat32,
    float2* __restrict__ ws) {
    const float2* __restrict__ blk = ws + WS_BLK;
    const int t = blockIdx.x * 256 + threadIdx.x;
    if (t < 131072) {                       // s8 (g=32): A then B half
        const int idx = t & 65535;
        const int half = t >> 16;
        const int b = idx >> 10, ci = (idx >> 5) & 31, cj = idx & 31;
        const int p0 = half ? max(2 * ci - 1, 0) : 2 * ci;
        const int q0 = half ? max(2 * cj - 1, 0) : 2 * cj;
        const float2 c = combine_blk<2>(blk, b, p0, q0);
        const float h = heat32[(size_t)(b + half * NB) * 1024 + ci * 32 + cj];
        ws[(half ? WS_B8 : WS_A8) + idx] = finish(c, h);
    } else if (t < 163840) {                // s16 (g=16)
        const int tt = t - 131072;
        const int idx = tt & 16383;
        const int half = tt >> 14;
        const int b = idx >> 8, ci = (idx >> 4) & 15, cj = idx & 15;
        const int p0 = half ? max(4 * ci - 1, 0) : 4 * ci;
        const int q0 = half ? max(4 * cj - 1, 0) : 4 * cj;
        const float2 c = combine_blk<4>(blk, b, p0, q0);
        const float h = heat16[(size_t)(b + half * NB) * 256 + ci * 16 + cj];
        ws[(half ? WS_B16 : WS_A16) + idx] = finish(c, h);
    } else {                                // s32 (g=8)
        const int tt = t - 163840;
        const int idx = tt & 4095;
        const int half = tt >> 12;
        const int b = idx >> 6, ci = (idx >> 3) & 7, cj = idx & 7;
        const int p0 = half ? max(8 * ci - 1, 0) : 8 * ci;
        const int q0 = half ? max(8 * cj - 1, 0) : 8 * cj;
        const float2 c = combine_blk<8>(blk, b, p0, q0);
        const float h = heat8[(size_t)(b + half * NB) * 64 + ci * 8 + cj];
        ws[(half ? WS_B32 : WS_A32) + idx] = finish(c, h);
    }
}

// Persistent phase-outer stream: 2048 blocks x 256 = 524288 threads.
// Each region = 1048576 float4 -> 2 grid-stride steps/thread/region.
// All 12 (phase,step) iterations fully unrolled; switch resolves at
// compile time -> straight-line code of 12 x {decode, load, fma, store}.
__global__ __launch_bounds__(256) void crops_stream_kernel(
    const float* __restrict__ img,
    const float2* __restrict__ ws,
    float* __restrict__ out) {
    const int tid = blockIdx.x * 256 + threadIdx.x;   // 0..524287
    float* __restrict__ c32 = out;                           // s=8 grid
    float* __restrict__ c16 = out + (size_t)NB2 * IMG2;      // s=16
    float* __restrict__ c8  = out + (size_t)2 * NB2 * IMG2;  // s=32

#pragma unroll
    for (int ph = 0; ph < 6; ++ph) {
#pragma unroll
        for (int k = 0; k < 2; ++k) {
            const int i  = tid + k * 524288;          // float4 index in region
            const int b  = i >> 14;
            const int u  = (i >> 6) & 255;
            const int v0 = (i & 63) << 2;
            const float* __restrict__ ip = img + (size_t)b * IMG2;

            int srow, scol;
            float2 st;
            float* optr;
            switch (ph) {
            case 0:
                srow = u; scol = v0;
                st = ws[WS_A8 + (b << 10) + ((u >> 3) << 5) + (v0 >> 3)];
                optr = c32 + (size_t)b * IMG2;
                break;
            case 1:
                srow = ((u >> 3) ? (u & ~7) - 4 : 0) + (u & 7);
                scol = (v0 < 8) ? v0 : v0 - 4;
                st = ws[WS_B8 + (b << 10) + ((u >> 3) << 5) + (v0 >> 3)];
                optr = c32 + (size_t)(b + NB) * IMG2;
                break;
            case 2:
                srow = u; scol = v0;
                st = ws[WS_A16 + (b << 8) + ((u >> 4) << 4) + (v0 >> 4)];
                optr = c16 + (size_t)b * IMG2;
                break;
            case 3:
                srow = ((u >> 4) ? (u & ~15) - 4 : 0) + (u & 15);
                scol = (v0 < 16) ? v0 : v0 - 4;
                st = ws[WS_B16 + (b << 8) + ((u >> 4) << 4) + (v0 >> 4)];
                optr = c16 + (size_t)(b + NB) * IMG2;
                break;
            case 4:
                srow = u; scol = v0;
                st = ws[WS_A32 + (b << 6) + ((u >> 5) << 3) + (v0 >> 5)];
                optr = c8 + (size_t)b * IMG2;
                break;
            default:
                srow = ((u >> 5) ? (u & ~31) - 4 : 0) + (u & 31);
                scol = (v0 < 32) ? v0 : v0 - 4;
                st = ws[WS_B32 + (b << 6) + ((u >> 5) << 3) + (v0 >> 5)];
                optr = c8 + (size_t)(b + NB) * IMG2;
                break;
            }
            const float4 q = *(const float4*)(ip + srow * IMG + scol);
            float4 o;
            o.x = (q.x - st.x) * st.y; o.y = (q.y - st.x) * st.y;
            o.z = (q.z - st.x) * st.y; o.w = (q.w - st.x) * st.y;
            *(float4*)(optr + u * IMG + v0) = o;
        }
    }
}

// ---------------------------------------------------------------------------
// label: one wave per row, 4 px per lane, float4 loads/stores. (R4, proven)
// ---------------------------------------------------------------------------
__device__ __forceinline__ void label_rows(
    const float* __restrict__ heat8,
    const float* __restrict__ heat16,
    const float* __restrict__ heat32,
    const float* __restrict__ seg8,
    const float* __restrict__ seg16,
    const float* __restrict__ seg32,
    float* __restrict__ out,
    int b, int u0) {
    const int wave = threadIdx.x >> 6;
    const int lane = threadIdx.x & 63;
    const int u    = u0 + wave;
    const int v0   = lane << 2;
    const int vs   = min(v0 + 4, 252);

    float nu[4] = {0.f, 0.f, 0.f, 0.f};
    float de[4] = {0.f, 0.f, 0.f, 0.f};

    if (u0 >= 32 && u0 <= 248) {
        const int i1 = u + 4;
#define SCALE_F(heat, seg, g, l, s)                                           \
        {                                                                     \
            const float* __restrict__ h1 = heat + b * (g * g);                \
            const float* __restrict__ h2 = heat + (NB + b) * (g * g);         \
            const float* __restrict__ r1 = seg + (size_t)b * IMG2 + u * IMG;  \
            const float* __restrict__ r2 =                                    \
                seg + (size_t)(NB + b) * IMG2 + i1 * IMG;                     \
            const float4 sd  = *(const float4*)(r1 + v0);                     \
            const float4 sg0 = *(const float4*)(r2 + v0);                     \
            const float4 sg1 = *(const float4*)(r2 + vs);                     \
            const float hd  = h1[(u >> l) * g + (v0 >> l)];                   \
            const float hg0 = h2[(i1 >> l) * g + (v0 >> l)];                  \
            const float hg1 = h2[(i1 >> l) * g + (vs >> l)];                  \
            const float md = (hd > 0.5f) ? 1.0f : 0.0f;                       \
            const float g0 = (hg0 > 0.5f) ? 1.0f : 0.0f;                      \
            const float g1 = (hg1 > 0.5f) ? 1.0f : 0.0f;                      \
            _Pragma("unroll")                                                 \
            for (int c = 0; c < 4; ++c) {                                     \
                const int v = v0 + c;                                         \
                const float m0 = (v < (s)) ? g0 : 0.0f;                       \
                const float m1 = (v >= (s) - 4 && v <= 251) ? g1 : 0.0f;      \
                float x = ((const float*)&sd)[c] * md;                        \
                x = fmaf(m0, ((const float*)&sg0)[c], x);                     \
                x = fmaf(m1, ((const float*)&sg1)[c], x);                     \
                nu[c] += x;                                                   \
                de[c] += md + m0 + m1;                                        \
            }                                                                 \
        }
        SCALE_F(heat32, seg32, 32, 3, 8)
        SCALE_F(heat16, seg16, 16, 4, 16)
        SCALE_F(heat8,  seg8,  8,  5, 32)
#undef SCALE_F
    } else {
        const int i0  = u;
        const int i1c = min(u + 4, 255);
#define SCALE_G(heat, seg, g, l, s)                                           \
        {                                                                     \
            const float* __restrict__ h1 = heat + b * (g * g);                \
            const float* __restrict__ h2 = heat + (NB + b) * (g * g);         \
            const float* __restrict__ r1 = seg + (size_t)b * IMG2 + u * IMG;  \
            const float* __restrict__ ra =                                    \
                seg + (size_t)(NB + b) * IMG2 + i0 * IMG;                     \
            const float* __restrict__ rb =                                    \
                seg + (size_t)(NB + b) * IMG2 + i1c * IMG;                    \
            const float4 sd  = *(const float4*)(r1 + v0);                     \
            const float4 a0q = *(const float4*)(ra + v0);                     \
            const float4 a1q = *(const float4*)(ra + vs);                     \
            const float4 b0q = *(const float4*)(rb + v0);                     \
            const float4 b1q = *(const float4*)(rb + vs);                     \
            const float hd  = h1[(u >> l) * g + (v0 >> l)];                   \
            const float hA0 = h2[(i0 >> l) * g + (v0 >> l)];                  \
            const float hA1 = h2[(i0 >> l) * g + (vs >> l)];                  \
            const float hB0 = h2[(i1c >> l) * g + (v0 >> l)];                 \
            const float hB1 = h2[(i1c >> l) * g + (vs >> l)];                 \
            const float miA = (u < (s)) ? 1.0f : 0.0f;                        \
            const float miB = (u >= (s) - 4 && u <= 251) ? 1.0f : 0.0f;       \
            const float md  = (hd > 0.5f) ? 1.0f : 0.0f;                      \
            const float gA0 = miA * ((hA0 > 0.5f) ? 1.0f : 0.0f);             \
            const float gA1 = miA * ((hA1 > 0.5f) ? 1.0f : 0.0f);             \
            const float gB0 = miB * ((hB0 > 0.5f) ? 1.0f : 0.0f);             \
            const float gB1 = miB * ((hB1 > 0.5f) ? 1.0f : 0.0f);             \
            _Pragma("unroll")                                                 \
            for (int c = 0; c < 4; ++c) {                                     \
                const int v = v0 + c;                                         \
                const float mj0 = (v < (s)) ? 1.0f : 0.0f;                    \
                const float mj1 = (v >= (s) - 4 && v <= 251) ? 1.0f : 0.0f;   \
                const float w00 = gA0 * mj0, w01 = gA1 * mj1;                 \
                const float w10 = gB0 * mj0, w11 = gB1 * mj1;                 \
                float x = ((const float*)&sd)[c] * md;                        \
                x = fmaf(w00, ((const float*)&a0q)[c], x);                    \
                x = fmaf(w01, ((const float*)&a1q)[c], x);                    \
                x = fmaf(w10, ((const float*)&b0q)[c], x);                    \
                x = fmaf(w11, ((const float*)&b1q)[c], x);                    \
                nu[c] += x;                                                   \
                de[c] += md + w00 + w01 + w10 + w11;                          \
            }                                                                 \
        }
        SCALE_G(heat32, seg32, 32, 3, 8)
        SCALE_G(heat16, seg16, 16, 4, 16)
        SCALE_G(heat8,  seg8,  8,  5, 32)
#undef SCALE_G
    }

    float4 o;
    o.x = nu[0] / (de[0] + 1e-10f);
    o.y = nu[1] / (de[1] + 1e-10f);
    o.z = nu[2] / (de[2] + 1e-10f);
    o.w = nu[3] / (de[3] + 1e-10f);
    *(float4*)(out + (size_t)b * IMG2 + u * IMG + v0) = o;
}

__global__ __launch_bounds__(256) void label_kernel(
    const float* __restrict__ heat8,
    const float* __restrict__ heat16,
    const float* __restrict__ heat32,
    const float* __restrict__ seg8,
    const float* __restrict__ seg16,
    const float* __restrict__ seg32,
    float* __restrict__ out) {
    float* label = out + (size_t)3 * NB2 * IMG2;    // (64,1,256,256)
    const int t  = blockIdx.x;                      // 0 .. 4095
    label_rows(heat8, heat16, heat32, seg8, seg16, seg32, label,
               t >> 6, (t & 63) << 2);
}

extern "C" void kernel_launch(void* const* d_in, const int* in_sizes, int n_in,
                              void* d_out, int out_size, void* d_ws, size_t ws_size,
                              hipStream_t stream) {
    const float* img    = (const float*)d_in[0];
    const float* heat8  = (const float*)d_in[1];
    const float* heat16 = (const float*)d_in[2];
    const float* heat32 = (const float*)d_in[3];
    const float* seg8   = (const float*)d_in[4];
    const float* seg16  = (const float*)d_in[5];
    const float* seg32  = (const float*)d_in[6];
    float2* ws = (float2*)d_ws;

    blk_kernel<<<dim3(1024), 256, 0, stream>>>(img, ws);
    cells_kernel<<<dim3(672), 256, 0, stream>>>(heat8, heat16, heat32, ws);
    crops_stream_kernel<<<dim3(2048), 256, 0, stream>>>(
        img, (const float2*)ws, (float*)d_out);
    label_kernel<<<dim3(4096), 256, 0, stream>>>(
        heat8, heat16, heat32, seg8, seg16, seg32, (float*)d_out);
}